// Round 6
// baseline (520.503 us; speedup 1.0000x reference)
//
#include <hip/hip_runtime.h>

constexpr int N   = 100000;   // nodes
constexpr int E   = 1600000;  // message edges
constexpr int EP  = 200000;   // pos scored edges
constexpr int ES  = 400000;   // total scored edges (pos+neg)
constexpr int CAP = 64;       // per-node in-edge bucket capacity (Poisson(16): P(deg>=64)~1e-18)
constexpr int XG  = 8;        // XCD groups for dst-partitioned bucket fill
constexpr int DRANGE = (N + XG - 1) / XG;   // 12500 nodes per group
constexpr int NGEMM = (N + 127) / 128;      // 782 gemm blocks
constexpr int NFILL = XG * (E / 256);       // 50000 fill blocks

typedef _Float16 f16x8 __attribute__((ext_vector_type(8)));
typedef _Float16 f16x4 __attribute__((ext_vector_type(4)));
typedef _Float16 f16x2 __attribute__((ext_vector_type(2)));
typedef float    f32x4 __attribute__((ext_vector_type(4)));

// ---------------------------------------------------------------- fused gemm1 + bucket fill
// Independent work, disjoint pipes (MFMA/LDS vs atomics/writes): one launch,
// gemm blocks first (long pole), fill blocks co-scheduled behind them.
//
// gemm part: H[100000,128](f16) = X @ W1 (f32->f16, fp32 accum), BM=128,
// BN=128, BK=32, register-prefetch pipeline (next global tile issued before
// the ds_read+MFMA of the current tile -> global latency hides under MFMA).
//
// fill part: XCD-routed dst partition — (bid-NGEMM)&7 groups land on one XCD
// each (round-robin dispatch heuristic), so each node's bucket line is
// written within a single L2 -> writes merge, one writeback per line.
__global__ __launch_bounds__(256) void gemm1_fill(const float* __restrict__ X,
                                                  const float* __restrict__ W1,
                                                  _Float16* __restrict__ H,
                                                  const int* __restrict__ ei,
                                                  int* __restrict__ cnt,
                                                  int* __restrict__ col) {
    if (blockIdx.x >= NGEMM) {
        // ---------------- bucket fill ----------------
        const int fb    = blockIdx.x - NGEMM;
        const int g     = fb & (XG - 1);
        const int chunk = fb >> 3;                  // 0..6249
        const int e     = chunk * 256 + threadIdx.x;
        const int d     = ei[E + e];                // edge_index[1] = dst
        const unsigned rel = (unsigned)(d - g * DRANGE);
        if (rel < (unsigned)DRANGE) {
            const int s = ei[e];                    // edge_index[0] = src
            const int p = atomicAdd(&cnt[d], 1);
            if (p < CAP) col[d * CAP + p] = s;
        }
        return;
    }
    // ---------------- gemm1 ----------------
    __shared__ _Float16 As[128][40];   // [m][k], stride 40 f16 = 80 B
    __shared__ _Float16 Bs[128][40];   // [n][k]  (W1 tile transposed)

    const int tid  = threadIdx.x;
    const int wave = tid >> 6;
    const int lane = tid & 63;
    const int m16  = lane & 15;
    const int quad = lane >> 4;
    const int blockRow = blockIdx.x * 128;

    f32x4 acc[2][8] = {};
    float4 av[4], bv[4];

    // preload tile k0=0 into registers
#pragma unroll
    for (int i = 0; i < 4; ++i) {
        int f  = tid + 256 * i;
        int r  = f >> 3;
        int gr = blockRow + r;
        av[i] = (gr < N) ? *(const float4*)&X[(size_t)gr * 256 + (f & 7) * 4]
                         : make_float4(0.f, 0.f, 0.f, 0.f);
        bv[i] = *(const float4*)&W1[(size_t)(f >> 5) * 128 + (f & 31) * 4];
    }

    for (int k0 = 0; k0 < 256; k0 += 32) {
        __syncthreads();     // previous iteration's LDS reads complete
        // ---- store staged registers (convert f32->f16)
#pragma unroll
        for (int i = 0; i < 4; ++i) {
            int f  = tid + 256 * i;
            int r  = f >> 3;
            int kq = f & 7;
            f16x4 h4;
            h4[0] = (_Float16)av[i].x; h4[1] = (_Float16)av[i].y;
            h4[2] = (_Float16)av[i].z; h4[3] = (_Float16)av[i].w;
            *(f16x4*)&As[r][kq * 4] = h4;
            int k  = f >> 5;
            int n4 = f & 31;
            Bs[n4 * 4 + 0][k] = (_Float16)bv[i].x;
            Bs[n4 * 4 + 1][k] = (_Float16)bv[i].y;
            Bs[n4 * 4 + 2][k] = (_Float16)bv[i].z;
            Bs[n4 * 4 + 3][k] = (_Float16)bv[i].w;
        }
        __syncthreads();
        // ---- issue next tile's global loads (overlap with MFMA below)
        if (k0 + 32 < 256) {
#pragma unroll
            for (int i = 0; i < 4; ++i) {
                int f  = tid + 256 * i;
                int r  = f >> 3;
                int gr = blockRow + r;
                av[i] = (gr < N) ? *(const float4*)&X[(size_t)gr * 256 + k0 + 32 + (f & 7) * 4]
                                 : make_float4(0.f, 0.f, 0.f, 0.f);
                bv[i] = *(const float4*)&W1[(size_t)(k0 + 32 + (f >> 5)) * 128 + (f & 31) * 4];
            }
        }
        // ---- compute on current LDS tile
        f16x8 afrag[2];
#pragma unroll
        for (int mt = 0; mt < 2; ++mt)
            afrag[mt] = *(const f16x8*)&As[wave * 32 + mt * 16 + m16][quad * 8];
#pragma unroll
        for (int nt = 0; nt < 8; ++nt) {
            f16x8 bfrag = *(const f16x8*)&Bs[nt * 16 + m16][quad * 8];
            acc[0][nt] = __builtin_amdgcn_mfma_f32_16x16x32_f16(afrag[0], bfrag, acc[0][nt], 0, 0, 0);
            acc[1][nt] = __builtin_amdgcn_mfma_f32_16x16x32_f16(afrag[1], bfrag, acc[1][nt], 0, 0, 0);
        }
    }
    // ---- epilogue: C/D layout col=lane&15, row=quad*4+r
#pragma unroll
    for (int mt = 0; mt < 2; ++mt) {
#pragma unroll
        for (int nt = 0; nt < 8; ++nt) {
#pragma unroll
            for (int r = 0; r < 4; ++r) {
                int gm = blockRow + wave * 32 + mt * 16 + quad * 4 + r;
                int gn = nt * 16 + m16;
                if (gm < N) H[(size_t)gm * 128 + gn] = (_Float16)acc[mt][nt][r];
            }
        }
    }
}

// ---------------------------------------------------------------- Fused agg1 + gemm2
// One wave per node; lane l owns feats [2l, 2l+1]. Depth-8 double-buffered
// software prefetch: 8 independent 256 B row loads in flight per wave
// (round 5 depth-4 gave 1.98 TB/s; Little's law -> deeper pipe, more BW).
__global__ __launch_bounds__(256) void agg1_gemm2(const _Float16* __restrict__ H,
                                                  const int* __restrict__ cnt,
                                                  const int* __restrict__ col,
                                                  const float* __restrict__ b1,
                                                  const float* __restrict__ W2,
                                                  float* __restrict__ Z) {
    const int n    = (blockIdx.x * blockDim.x + threadIdx.x) >> 6;
    const int lane = threadIdx.x & 63;
    if (n >= N) return;
    const int c = min(cnt[n], CAP);

    int sv = n;
    if (lane < c) sv = col[n * CAP + lane];
    const float dvw = rsqrtf((float)cnt[sv] + 1.0f);
    const float dv  = (lane <= c) ? dvw : 0.0f;

    const _Float16* hbase = H + lane * 2;
    const int ned8 = (c + 1 + 7) & ~7;      // octets of 8 edges

    f16x2 va[8]; float wa[8];
#pragma unroll
    for (int t = 0; t < 8; ++t) {
        const int   e = min(t, 63);
        const int   s = __shfl(sv, e);
        wa[t]         = __shfl(dv, e);
        va[t] = *(const f16x2*)&hbase[(size_t)s * 128];
    }
    float ax = 0.f, ay = 0.f;
    for (int j = 8; j < ned8; j += 8) {
        f16x2 vb[8]; float wb[8];
#pragma unroll
        for (int t = 0; t < 8; ++t) {       // issue next octet's 8 loads
            const int   e = min(j + t, 63);
            const int   s = __shfl(sv, e);
            wb[t]         = __shfl(dv, e);
            vb[t] = *(const f16x2*)&hbase[(size_t)s * 128];
        }
#pragma unroll
        for (int t = 0; t < 8; ++t) {       // consume current octet
            ax = fmaf(wa[t], (float)va[t][0], ax);
            ay = fmaf(wa[t], (float)va[t][1], ay);
            va[t] = vb[t]; wa[t] = wb[t];
        }
    }
#pragma unroll
    for (int t = 0; t < 8; ++t) {           // drain last octet
        ax = fmaf(wa[t], (float)va[t][0], ax);
        ay = fmaf(wa[t], (float)va[t][1], ay);
    }

    const float dn = __shfl(dv, c);         // dinv[n]
    const float2 b = *(const float2*)&b1[lane * 2];
    const float hr0 = fmaxf(ax * dn + b.x, 0.f);
    const float hr1 = fmaxf(ay * dn + b.y, 0.f);

    // gemm2 partial: lane covers W2 rows 2l, 2l+1
    const float4 wa0 = *(const float4*)&W2[(size_t)(lane * 2) * 8];
    const float4 wa1 = *(const float4*)&W2[(size_t)(lane * 2) * 8 + 4];
    const float4 wb0 = *(const float4*)&W2[(size_t)(lane * 2 + 1) * 8];
    const float4 wb1 = *(const float4*)&W2[(size_t)(lane * 2 + 1) * 8 + 4];
    float p[8];
    p[0] = hr0 * wa0.x + hr1 * wb0.x;
    p[1] = hr0 * wa0.y + hr1 * wb0.y;
    p[2] = hr0 * wa0.z + hr1 * wb0.z;
    p[3] = hr0 * wa0.w + hr1 * wb0.w;
    p[4] = hr0 * wa1.x + hr1 * wb1.x;
    p[5] = hr0 * wa1.y + hr1 * wb1.y;
    p[6] = hr0 * wa1.z + hr1 * wb1.z;
    p[7] = hr0 * wa1.w + hr1 * wb1.w;
#pragma unroll
    for (int off = 32; off > 0; off >>= 1) {
#pragma unroll
        for (int j = 0; j < 8; ++j) p[j] += __shfl_xor(p[j], off);
    }
    if (lane == 0) {
        *(float4*)&Z[(size_t)n * 8]     = make_float4(p[0], p[1], p[2], p[3]);
        *(float4*)&Z[(size_t)n * 8 + 4] = make_float4(p[4], p[5], p[6], p[7]);
    }
}

// ---------------------------------------------------------------- Aggregation layer 2 (F=8)
// One thread per node, depth-4 prefetch of (src, Z-row) to overlap misses.
__global__ __launch_bounds__(256) void agg2(const float* __restrict__ Z,
                                            const int* __restrict__ cnt,
                                            const int* __restrict__ col,
                                            const float* __restrict__ b2,
                                            float* __restrict__ ZA) {
    const int n = blockIdx.x * blockDim.x + threadIdx.x;
    if (n >= N) return;
    const int c = min(cnt[n], CAP);
    float acc[8] = {};

    float4 va0[4], va1[4]; float wv[4];
#pragma unroll
    for (int t = 0; t < 4; ++t) {
        const int s = (t < c) ? col[n * CAP + t] : n;
        wv[t]  = (t < c) ? rsqrtf((float)cnt[s] + 1.0f) : 0.0f;
        va0[t] = *(const float4*)&Z[(size_t)s * 8];
        va1[t] = *(const float4*)&Z[(size_t)s * 8 + 4];
    }
    int j = 4;
    for (; j + 4 <= c + 4; j += 4) {
        float4 vb0[4], vb1[4]; float wb[4];
#pragma unroll
        for (int t = 0; t < 4; ++t) {
            const int jt = j + t;
            const int s  = (jt < c) ? col[n * CAP + jt] : n;
            wb[t]  = (jt < c) ? rsqrtf((float)cnt[s] + 1.0f) : 0.0f;
            vb0[t] = *(const float4*)&Z[(size_t)s * 8];
            vb1[t] = *(const float4*)&Z[(size_t)s * 8 + 4];
        }
#pragma unroll
        for (int t = 0; t < 4; ++t) {
            const float w = wv[t];
            acc[0] = fmaf(w, va0[t].x, acc[0]); acc[1] = fmaf(w, va0[t].y, acc[1]);
            acc[2] = fmaf(w, va0[t].z, acc[2]); acc[3] = fmaf(w, va0[t].w, acc[3]);
            acc[4] = fmaf(w, va1[t].x, acc[4]); acc[5] = fmaf(w, va1[t].y, acc[5]);
            acc[6] = fmaf(w, va1[t].z, acc[6]); acc[7] = fmaf(w, va1[t].w, acc[7]);
            va0[t] = vb0[t]; va1[t] = vb1[t]; wv[t] = wb[t];
        }
    }
#pragma unroll
    for (int t = 0; t < 4; ++t) {
        const float w = wv[t];
        acc[0] = fmaf(w, va0[t].x, acc[0]); acc[1] = fmaf(w, va0[t].y, acc[1]);
        acc[2] = fmaf(w, va0[t].z, acc[2]); acc[3] = fmaf(w, va0[t].w, acc[3]);
        acc[4] = fmaf(w, va1[t].x, acc[4]); acc[5] = fmaf(w, va1[t].y, acc[5]);
        acc[6] = fmaf(w, va1[t].z, acc[6]); acc[7] = fmaf(w, va1[t].w, acc[7]);
    }

    const float dn = rsqrtf((float)c + 1.0f);
    const float4 zn0 = *(const float4*)&Z[(size_t)n * 8];
    const float4 zn1 = *(const float4*)&Z[(size_t)n * 8 + 4];
    float o[8];
    o[0] = (acc[0] + dn * zn0.x) * dn + b2[0];
    o[1] = (acc[1] + dn * zn0.y) * dn + b2[1];
    o[2] = (acc[2] + dn * zn0.z) * dn + b2[2];
    o[3] = (acc[3] + dn * zn0.w) * dn + b2[3];
    o[4] = (acc[4] + dn * zn1.x) * dn + b2[4];
    o[5] = (acc[5] + dn * zn1.y) * dn + b2[5];
    o[6] = (acc[6] + dn * zn1.z) * dn + b2[6];
    o[7] = (acc[7] + dn * zn1.w) * dn + b2[7];
    *(float4*)&ZA[(size_t)n * 8]     = make_float4(o[0], o[1], o[2], o[3]);
    *(float4*)&ZA[(size_t)n * 8 + 4] = make_float4(o[4], o[5], o[6], o[7]);
}

// ---------------------------------------------------------------- Edge scoring
__global__ __launch_bounds__(256) void score(const float* __restrict__ ZA,
                                             const int* __restrict__ pe,
                                             const int* __restrict__ ne,
                                             float* __restrict__ out) {
    const int e = blockIdx.x * blockDim.x + threadIdx.x;
    if (e >= ES) return;
    int a, b;
    if (e < EP) { a = pe[e];      b = pe[EP + e]; }
    else        { a = ne[e - EP]; b = ne[e];      }
    const float4 xa0 = *(const float4*)&ZA[(size_t)a * 8];
    const float4 xa1 = *(const float4*)&ZA[(size_t)a * 8 + 4];
    const float4 xb0 = *(const float4*)&ZA[(size_t)b * 8];
    const float4 xb1 = *(const float4*)&ZA[(size_t)b * 8 + 4];
    out[e] = xa0.x * xb0.x + xa0.y * xb0.y + xa0.z * xb0.z + xa0.w * xb0.w +
             xa1.x * xb1.x + xa1.y * xb1.y + xa1.z * xb1.z + xa1.w * xb1.w;
}

// ---------------------------------------------------------------- launch

extern "C" void kernel_launch(void* const* d_in, const int* in_sizes, int n_in,
                              void* d_out, int out_size, void* d_ws, size_t ws_size,
                              hipStream_t stream) {
    const float* x  = (const float*)d_in[0];
    const int*   ei = (const int*)d_in[1];   // [2, 1.6M] row-major
    const int*   pe = (const int*)d_in[2];   // [2, 200k]
    const int*   ne = (const int*)d_in[3];   // [2, 200k]
    const float* W1 = (const float*)d_in[4];
    const float* b1 = (const float*)d_in[5];
    const float* W2 = (const float*)d_in[6];
    const float* b2 = (const float*)d_in[7];
    float* out = (float*)d_out;

    char* ws = (char*)d_ws;
    size_t off = 0;
    auto carve = [&](size_t bytes) {
        char* p = ws + off;
        off += (bytes + 255) & ~(size_t)255;
        return p;
    };
    int*       cnt  = (int*)      carve((size_t)N * sizeof(int));           // 0.4 MB
    int*       col  = (int*)      carve((size_t)N * CAP * sizeof(int));     // 25.6 MB
    _Float16*  H    = (_Float16*) carve((size_t)N * 128 * sizeof(_Float16));// 25.6 MB
    float*     Z    = (float*)    carve((size_t)N * 8 * sizeof(float));     // 3.2 MB
    float*     ZA   = (float*)    carve((size_t)N * 8 * sizeof(float));     // 3.2 MB

    hipMemsetAsync(cnt, 0, (size_t)N * sizeof(int), stream);
    gemm1_fill  <<<NGEMM + NFILL, 256, 0, stream>>>(x, W1, H, ei, cnt, col);
    agg1_gemm2  <<<(N * 64 + 255) / 256, 256, 0, stream>>>(H, cnt, col, b1, W2, Z);
    agg2        <<<(N + 255) / 256, 256, 0, stream>>>(Z, cnt, col, b2, ZA);
    score       <<<(ES + 255) / 256, 256, 0, stream>>>(ZA, pe, ne, out);
}

// Round 7
// 445.330 us; speedup vs baseline: 1.1688x; 1.1688x over previous
//
#include <hip/hip_runtime.h>

constexpr int N   = 100000;   // nodes
constexpr int E   = 1600000;  // message edges
constexpr int EP  = 200000;   // pos scored edges
constexpr int ES  = 400000;   // total scored edges (pos+neg)
constexpr int CAP = 64;       // per-node in-edge bucket capacity (Poisson(16): P(deg>=64)~1e-18)
constexpr int XG  = 8;        // XCD groups for dst-partitioned bucket fill
constexpr int DRANGE = (N + XG - 1) / XG;   // 12500 nodes per group

typedef _Float16 f16x8 __attribute__((ext_vector_type(8)));
typedef _Float16 f16x4 __attribute__((ext_vector_type(4)));
typedef _Float16 f16x2 __attribute__((ext_vector_type(2)));
typedef float    f32x4 __attribute__((ext_vector_type(4)));

// ---------------------------------------------------------------- bucket fill
// Standalone (4 VGPR -> high occupancy; round-6 fusion with gemm cost 3.5x
// occupancy and regressed). XCD-routed: blockIdx%8 round-robins XCDs (perf
// heuristic only); group g claims dst in [g*12500,(g+1)*12500) so each
// node's bucket line is written within one L2 -> writes merge, one
// writeback per line (round 2->3: WRITE_SIZE 96 MB -> ~26 MB).
__global__ __launch_bounds__(256) void fill_buckets(const int* __restrict__ ei,
                                                    int* __restrict__ cnt,
                                                    int* __restrict__ col) {
    const int g     = blockIdx.x & (XG - 1);
    const int chunk = blockIdx.x >> 3;          // 0..6249
    const int e     = chunk * 256 + threadIdx.x;
    const int d     = ei[E + e];                // edge_index[1] = dst
    const unsigned rel = (unsigned)(d - g * DRANGE);
    if (rel < (unsigned)DRANGE) {
        const int s = ei[e];                    // edge_index[0] = src
        const int p = atomicAdd(&cnt[d], 1);
        if (p < CAP) col[d * CAP + p] = s;
    }
}

// ---------------------------------------------------------------- GEMM1 (f16 MFMA)
// H[100000,128](f16) = X @ W1 (f32->f16, fp32 accum), BM=128, BN=128, BK=32.
// Register-prefetch pipeline: tile k+1's global loads issue before tile k's
// ds_read+MFMA, so global latency hides under compute.
__global__ __launch_bounds__(256) void gemm1_mfma(const float* __restrict__ X,
                                                  const float* __restrict__ W1,
                                                  _Float16* __restrict__ H) {
    __shared__ _Float16 As[128][40];   // [m][k], stride 40 f16 = 80 B
    __shared__ _Float16 Bs[128][40];   // [n][k]  (W1 tile transposed)

    const int tid  = threadIdx.x;
    const int wave = tid >> 6;
    const int lane = tid & 63;
    const int m16  = lane & 15;
    const int quad = lane >> 4;
    const int blockRow = blockIdx.x * 128;

    f32x4 acc[2][8] = {};
    float4 av[4], bv[4];

    // preload tile k0=0 into registers
#pragma unroll
    for (int i = 0; i < 4; ++i) {
        int f  = tid + 256 * i;
        int r  = f >> 3;
        int gr = blockRow + r;
        av[i] = (gr < N) ? *(const float4*)&X[(size_t)gr * 256 + (f & 7) * 4]
                         : make_float4(0.f, 0.f, 0.f, 0.f);
        bv[i] = *(const float4*)&W1[(size_t)(f >> 5) * 128 + (f & 31) * 4];
    }

    for (int k0 = 0; k0 < 256; k0 += 32) {
        __syncthreads();     // previous iteration's LDS reads complete
        // ---- store staged registers (convert f32->f16)
#pragma unroll
        for (int i = 0; i < 4; ++i) {
            int f  = tid + 256 * i;
            int r  = f >> 3;
            int kq = f & 7;
            f16x4 h4;
            h4[0] = (_Float16)av[i].x; h4[1] = (_Float16)av[i].y;
            h4[2] = (_Float16)av[i].z; h4[3] = (_Float16)av[i].w;
            *(f16x4*)&As[r][kq * 4] = h4;
            int k  = f >> 5;
            int n4 = f & 31;
            Bs[n4 * 4 + 0][k] = (_Float16)bv[i].x;
            Bs[n4 * 4 + 1][k] = (_Float16)bv[i].y;
            Bs[n4 * 4 + 2][k] = (_Float16)bv[i].z;
            Bs[n4 * 4 + 3][k] = (_Float16)bv[i].w;
        }
        __syncthreads();
        // ---- issue next tile's global loads (overlap with MFMA below)
        if (k0 + 32 < 256) {
#pragma unroll
            for (int i = 0; i < 4; ++i) {
                int f  = tid + 256 * i;
                int r  = f >> 3;
                int gr = blockRow + r;
                av[i] = (gr < N) ? *(const float4*)&X[(size_t)gr * 256 + k0 + 32 + (f & 7) * 4]
                                 : make_float4(0.f, 0.f, 0.f, 0.f);
                bv[i] = *(const float4*)&W1[(size_t)(k0 + 32 + (f >> 5)) * 128 + (f & 31) * 4];
            }
        }
        // ---- compute on current LDS tile
        f16x8 afrag[2];
#pragma unroll
        for (int mt = 0; mt < 2; ++mt)
            afrag[mt] = *(const f16x8*)&As[wave * 32 + mt * 16 + m16][quad * 8];
#pragma unroll
        for (int nt = 0; nt < 8; ++nt) {
            f16x8 bfrag = *(const f16x8*)&Bs[nt * 16 + m16][quad * 8];
            acc[0][nt] = __builtin_amdgcn_mfma_f32_16x16x32_f16(afrag[0], bfrag, acc[0][nt], 0, 0, 0);
            acc[1][nt] = __builtin_amdgcn_mfma_f32_16x16x32_f16(afrag[1], bfrag, acc[1][nt], 0, 0, 0);
        }
    }
    // ---- epilogue: C/D layout col=lane&15, row=quad*4+r
#pragma unroll
    for (int mt = 0; mt < 2; ++mt) {
#pragma unroll
        for (int nt = 0; nt < 8; ++nt) {
#pragma unroll
            for (int r = 0; r < 4; ++r) {
                int gm = blockRow + wave * 32 + mt * 16 + quad * 4 + r;
                int gn = nt * 16 + m16;
                if (gm < N) H[(size_t)gm * 128 + gn] = (_Float16)acc[mt][nt][r];
            }
        }
    }
}

// ---------------------------------------------------------------- Fused agg1 + gemm2
// One wave per node; lane l owns feats [2l, 2l+1]. Depth-8 double-buffered
// software prefetch: 8 independent 256 B row loads in flight per wave
// (depth-4 measured 1.98 TB/s; Little's law -> deeper pipe, more BW).
__global__ __launch_bounds__(256) void agg1_gemm2(const _Float16* __restrict__ H,
                                                  const int* __restrict__ cnt,
                                                  const int* __restrict__ col,
                                                  const float* __restrict__ b1,
                                                  const float* __restrict__ W2,
                                                  float* __restrict__ Z) {
    const int n    = (blockIdx.x * blockDim.x + threadIdx.x) >> 6;
    const int lane = threadIdx.x & 63;
    if (n >= N) return;
    const int c = min(cnt[n], CAP);

    int sv = n;
    if (lane < c) sv = col[n * CAP + lane];
    const float dvw = rsqrtf((float)cnt[sv] + 1.0f);
    const float dv  = (lane <= c) ? dvw : 0.0f;

    const _Float16* hbase = H + lane * 2;
    const int ned8 = (c + 1 + 7) & ~7;      // octets of 8 edges

    f16x2 va[8]; float wa[8];
#pragma unroll
    for (int t = 0; t < 8; ++t) {
        const int   e = min(t, 63);
        const int   s = __shfl(sv, e);
        wa[t]         = __shfl(dv, e);
        va[t] = *(const f16x2*)&hbase[(size_t)s * 128];
    }
    float ax = 0.f, ay = 0.f;
    for (int j = 8; j < ned8; j += 8) {
        f16x2 vb[8]; float wb[8];
#pragma unroll
        for (int t = 0; t < 8; ++t) {       // issue next octet's 8 loads
            const int   e = min(j + t, 63);
            const int   s = __shfl(sv, e);
            wb[t]         = __shfl(dv, e);
            vb[t] = *(const f16x2*)&hbase[(size_t)s * 128];
        }
#pragma unroll
        for (int t = 0; t < 8; ++t) {       // consume current octet
            ax = fmaf(wa[t], (float)va[t][0], ax);
            ay = fmaf(wa[t], (float)va[t][1], ay);
            va[t] = vb[t]; wa[t] = wb[t];
        }
    }
#pragma unroll
    for (int t = 0; t < 8; ++t) {           // drain last octet
        ax = fmaf(wa[t], (float)va[t][0], ax);
        ay = fmaf(wa[t], (float)va[t][1], ay);
    }

    const float dn = __shfl(dv, c);         // dinv[n]
    const float2 b = *(const float2*)&b1[lane * 2];
    const float hr0 = fmaxf(ax * dn + b.x, 0.f);
    const float hr1 = fmaxf(ay * dn + b.y, 0.f);

    // gemm2 partial: lane covers W2 rows 2l, 2l+1
    const float4 wa0 = *(const float4*)&W2[(size_t)(lane * 2) * 8];
    const float4 wa1 = *(const float4*)&W2[(size_t)(lane * 2) * 8 + 4];
    const float4 wb0 = *(const float4*)&W2[(size_t)(lane * 2 + 1) * 8];
    const float4 wb1 = *(const float4*)&W2[(size_t)(lane * 2 + 1) * 8 + 4];
    float p[8];
    p[0] = hr0 * wa0.x + hr1 * wb0.x;
    p[1] = hr0 * wa0.y + hr1 * wb0.y;
    p[2] = hr0 * wa0.z + hr1 * wb0.z;
    p[3] = hr0 * wa0.w + hr1 * wb0.w;
    p[4] = hr0 * wa1.x + hr1 * wb1.x;
    p[5] = hr0 * wa1.y + hr1 * wb1.y;
    p[6] = hr0 * wa1.z + hr1 * wb1.z;
    p[7] = hr0 * wa1.w + hr1 * wb1.w;
#pragma unroll
    for (int off = 32; off > 0; off >>= 1) {
#pragma unroll
        for (int j = 0; j < 8; ++j) p[j] += __shfl_xor(p[j], off);
    }
    if (lane == 0) {
        *(float4*)&Z[(size_t)n * 8]     = make_float4(p[0], p[1], p[2], p[3]);
        *(float4*)&Z[(size_t)n * 8 + 4] = make_float4(p[4], p[5], p[6], p[7]);
    }
}

// ---------------------------------------------------------------- Aggregation layer 2 (F=8)
// One thread per node, depth-4 prefetch of (src, Z-row) to overlap misses.
__global__ __launch_bounds__(256) void agg2(const float* __restrict__ Z,
                                            const int* __restrict__ cnt,
                                            const int* __restrict__ col,
                                            const float* __restrict__ b2,
                                            float* __restrict__ ZA) {
    const int n = blockIdx.x * blockDim.x + threadIdx.x;
    if (n >= N) return;
    const int c = min(cnt[n], CAP);
    float acc[8] = {};

    float4 va0[4], va1[4]; float wv[4];
#pragma unroll
    for (int t = 0; t < 4; ++t) {
        const int s = (t < c) ? col[n * CAP + t] : n;
        wv[t]  = (t < c) ? rsqrtf((float)cnt[s] + 1.0f) : 0.0f;
        va0[t] = *(const float4*)&Z[(size_t)s * 8];
        va1[t] = *(const float4*)&Z[(size_t)s * 8 + 4];
    }
    int j = 4;
    for (; j + 4 <= c + 4; j += 4) {
        float4 vb0[4], vb1[4]; float wb[4];
#pragma unroll
        for (int t = 0; t < 4; ++t) {
            const int jt = j + t;
            const int s  = (jt < c) ? col[n * CAP + jt] : n;
            wb[t]  = (jt < c) ? rsqrtf((float)cnt[s] + 1.0f) : 0.0f;
            vb0[t] = *(const float4*)&Z[(size_t)s * 8];
            vb1[t] = *(const float4*)&Z[(size_t)s * 8 + 4];
        }
#pragma unroll
        for (int t = 0; t < 4; ++t) {
            const float w = wv[t];
            acc[0] = fmaf(w, va0[t].x, acc[0]); acc[1] = fmaf(w, va0[t].y, acc[1]);
            acc[2] = fmaf(w, va0[t].z, acc[2]); acc[3] = fmaf(w, va0[t].w, acc[3]);
            acc[4] = fmaf(w, va1[t].x, acc[4]); acc[5] = fmaf(w, va1[t].y, acc[5]);
            acc[6] = fmaf(w, va1[t].z, acc[6]); acc[7] = fmaf(w, va1[t].w, acc[7]);
            va0[t] = vb0[t]; va1[t] = vb1[t]; wv[t] = wb[t];
        }
    }
#pragma unroll
    for (int t = 0; t < 4; ++t) {
        const float w = wv[t];
        acc[0] = fmaf(w, va0[t].x, acc[0]); acc[1] = fmaf(w, va0[t].y, acc[1]);
        acc[2] = fmaf(w, va0[t].z, acc[2]); acc[3] = fmaf(w, va0[t].w, acc[3]);
        acc[4] = fmaf(w, va1[t].x, acc[4]); acc[5] = fmaf(w, va1[t].y, acc[5]);
        acc[6] = fmaf(w, va1[t].z, acc[6]); acc[7] = fmaf(w, va1[t].w, acc[7]);
    }

    const float dn = rsqrtf((float)c + 1.0f);
    const float4 zn0 = *(const float4*)&Z[(size_t)n * 8];
    const float4 zn1 = *(const float4*)&Z[(size_t)n * 8 + 4];
    float o[8];
    o[0] = (acc[0] + dn * zn0.x) * dn + b2[0];
    o[1] = (acc[1] + dn * zn0.y) * dn + b2[1];
    o[2] = (acc[2] + dn * zn0.z) * dn + b2[2];
    o[3] = (acc[3] + dn * zn0.w) * dn + b2[3];
    o[4] = (acc[4] + dn * zn1.x) * dn + b2[4];
    o[5] = (acc[5] + dn * zn1.y) * dn + b2[5];
    o[6] = (acc[6] + dn * zn1.z) * dn + b2[6];
    o[7] = (acc[7] + dn * zn1.w) * dn + b2[7];
    *(float4*)&ZA[(size_t)n * 8]     = make_float4(o[0], o[1], o[2], o[3]);
    *(float4*)&ZA[(size_t)n * 8 + 4] = make_float4(o[4], o[5], o[6], o[7]);
}

// ---------------------------------------------------------------- Edge scoring
__global__ __launch_bounds__(256) void score(const float* __restrict__ ZA,
                                             const int* __restrict__ pe,
                                             const int* __restrict__ ne,
                                             float* __restrict__ out) {
    const int e = blockIdx.x * blockDim.x + threadIdx.x;
    if (e >= ES) return;
    int a, b;
    if (e < EP) { a = pe[e];      b = pe[EP + e]; }
    else        { a = ne[e - EP]; b = ne[e];      }
    const float4 xa0 = *(const float4*)&ZA[(size_t)a * 8];
    const float4 xa1 = *(const float4*)&ZA[(size_t)a * 8 + 4];
    const float4 xb0 = *(const float4*)&ZA[(size_t)b * 8];
    const float4 xb1 = *(const float4*)&ZA[(size_t)b * 8 + 4];
    out[e] = xa0.x * xb0.x + xa0.y * xb0.y + xa0.z * xb0.z + xa0.w * xb0.w +
             xa1.x * xb1.x + xa1.y * xb1.y + xa1.z * xb1.z + xa1.w * xb1.w;
}

// ---------------------------------------------------------------- launch

extern "C" void kernel_launch(void* const* d_in, const int* in_sizes, int n_in,
                              void* d_out, int out_size, void* d_ws, size_t ws_size,
                              hipStream_t stream) {
    const float* x  = (const float*)d_in[0];
    const int*   ei = (const int*)d_in[1];   // [2, 1.6M] row-major
    const int*   pe = (const int*)d_in[2];   // [2, 200k]
    const int*   ne = (const int*)d_in[3];   // [2, 200k]
    const float* W1 = (const float*)d_in[4];
    const float* b1 = (const float*)d_in[5];
    const float* W2 = (const float*)d_in[6];
    const float* b2 = (const float*)d_in[7];
    float* out = (float*)d_out;

    char* ws = (char*)d_ws;
    size_t off = 0;
    auto carve = [&](size_t bytes) {
        char* p = ws + off;
        off += (bytes + 255) & ~(size_t)255;
        return p;
    };
    int*       cnt  = (int*)      carve((size_t)N * sizeof(int));           // 0.4 MB
    int*       col  = (int*)      carve((size_t)N * CAP * sizeof(int));     // 25.6 MB
    _Float16*  H    = (_Float16*) carve((size_t)N * 128 * sizeof(_Float16));// 25.6 MB
    float*     Z    = (float*)    carve((size_t)N * 8 * sizeof(float));     // 3.2 MB
    float*     ZA   = (float*)    carve((size_t)N * 8 * sizeof(float));     // 3.2 MB

    hipMemsetAsync(cnt, 0, (size_t)N * sizeof(int), stream);
    fill_buckets<<<XG * (E / 256), 256, 0, stream>>>(ei, cnt, col);
    gemm1_mfma  <<<(N + 127) / 128, 256, 0, stream>>>(x, W1, H);
    agg1_gemm2  <<<(N * 64 + 255) / 256, 256, 0, stream>>>(H, cnt, col, b1, W2, Z);
    agg2        <<<(N + 255) / 256, 256, 0, stream>>>(Z, cnt, col, b2, ZA);
    score       <<<(ES + 255) / 256, 256, 0, stream>>>(ZA, pe, ne, out);
}